// Round 12
// baseline (95.950 us; speedup 1.0000x reference)
//
#include <hip/hip_runtime.h>

#define BATCH 4
#define SEQ   2048
#define EMB   128
#define NH    16
#define DK    8

// log2(e) / sqrt(8): fold softmax temperature into exp2 (pre-multiplied into qf)
#define QSCALE 0.510069726f

typedef _Float16 v2h __attribute__((ext_vector_type(2)));
typedef _Float16 v4h __attribute__((ext_vector_type(4)));
typedef __fp16   v2fp __attribute__((ext_vector_type(2)));
typedef float    v4f __attribute__((ext_vector_type(4)));

#define CHUNK  512          // keys per LDS stage (4 stages cover SEQ)
#define NCHUNK (SEQ / CHUNK)
#define VTP    520          // VT row pitch (f16): 260 words, breaks pow2 stride

// ---------------------------------------------------------------------------
// Fused features + MFMA attention.
// Block = 256 thr = 4 waves; wave owns 32 q-rows (2 16-row tiles).
// Grid = 64 bh x 16 = 1024 blocks; LDS 24.6 KB.
//
// Staging: thread owns keys {tid, tid+256} of the chunk -> BOTH Kl b128
// writes are 16 B/lane stride (measured conflict-free on gfx950; the R11
// 32 B stride cost 4.5M conflict cycles). VT written as b16 at [d][key]:
// lane-consecutive, 2 lanes/bank = free. x loads for chunk c+1 are issued
// right after the stage barrier and consumed a full compute phase later
// (software pipeline) so no HBM/L2 latency sits between barriers.
//
// Per 16-key tile: S^T = mfma_16x16x16_f16(A=K, B=Q^T). C-layout {q=L&15,
// key=quad*4+r} == B-frag layout {n=L&15, k=quad*4+j}, so P = exp2(S^T)
// feeds out^T = mfma(A=V^T, B=P^T, acc) entirely in registers (pkrtz pack).
// No zero-select on K frag: qf is 0 in quads 2-3, padded-K garbage * 0.
// Ones-row d=8 of V^T gives the softmax denominator for free.
// Plain-exp softmax is exact here: |score*log2e/sqrt8| <= 4.1 (features <=1).
// ---------------------------------------------------------------------------
__launch_bounds__(256, 6)
__global__ void attn_kernel(const float* __restrict__ x,
                            const float* __restrict__ theta,
                            _Float16* __restrict__ Ah /* [B*S][128] f16 */) {
  __shared__ __align__(16) _Float16 Kl[CHUNK * 8];   // 8 KB: [key][8 dims]
  __shared__ __align__(16) _Float16 VT[16][VTP];     // 16.6 KB: [d][key]

  const int tid  = threadIdx.x;
  const int L    = tid & 63;
  const int quad = L >> 4;
  const int ln   = L & 15;
  const int wv   = tid >> 6;        // wave 0..3
  const int bh     = blockIdx.x >> 4;
  const int qchunk = blockIdx.x & 15;
  const int qb     = qchunk * 128 + wv * 32;   // wave's 32 q rows
  const int b = bh >> 4;
  const int h = bh & 15;

  float th[DK];
#pragma unroll
  for (int i = 0; i < DK; ++i) th[i] = theta[i];

  // one-time init: VT row 8 = 1.0 (denominator), rows 9-15 = 0
  for (int i = tid; i < 8 * VTP / 4; i += 256) {
    v4h v = (i < VTP / 4) ? (v4h){(_Float16)1.f, (_Float16)1.f,
                                  (_Float16)1.f, (_Float16)1.f}
                          : (v4h){0, 0, 0, 0};
    *(v4h*)(&VT[8][0] + i * 4) = v;
  }

  const int c0 = qchunk >> 2;       // chunk containing this block's q rows
  const float* xb = x + (size_t)b * SEQ * EMB + h * DK;

  // prefetch chunk c0's x rows (keys tid, tid+256)
  float4 pa0, pa1, pb0, pb1;
  {
    const float* xp = xb + (size_t)(c0 * CHUNK + tid) * EMB;
    pa0 = *(const float4*)(xp);
    pa1 = *(const float4*)(xp + 4);
    pb0 = *(const float4*)(xp + 256 * EMB);
    pb1 = *(const float4*)(xp + 256 * EMB + 4);
  }

  v4h qf[2] = {{0, 0, 0, 0}, {0, 0, 0, 0}};
  v4f acc[2];
  acc[0] = (v4f){0.f, 0.f, 0.f, 0.f};
  acc[1] = (v4f){0.f, 0.f, 0.f, 0.f};
  const v4f zf = (v4f){0.f, 0.f, 0.f, 0.f};

  for (int cc = 0; cc < NCHUNK; ++cc) {
    if (cc) __syncthreads();        // all waves done computing previous chunk

    // ---- stage: features for keys tid, tid+256 from prefetched regs ----
    {
      float r0[8], r1[8];
      r0[0] = __cosf(pa0.x + th[0]);
      r0[1] = r0[0] * __cosf(pa0.y + th[1]);
      r0[2] = r0[1] * __cosf(pa0.z + th[2]);
      r0[3] = r0[2] * __cosf(pa0.w + th[3]);
      r0[4] = r0[3] * __cosf(pa1.x + th[4]);
      r0[5] = r0[4] * __cosf(pa1.y + th[5]);
      r0[6] = r0[5] * __cosf(pa1.z + th[6]);
      r0[7] = r0[6] * __cosf(pa1.w + th[7]);
      r1[0] = __cosf(pb0.x + th[0]);
      r1[1] = r1[0] * __cosf(pb0.y + th[1]);
      r1[2] = r1[1] * __cosf(pb0.z + th[2]);
      r1[3] = r1[2] * __cosf(pb0.w + th[3]);
      r1[4] = r1[3] * __cosf(pb1.x + th[4]);
      r1[5] = r1[4] * __cosf(pb1.y + th[5]);
      r1[6] = r1[5] * __cosf(pb1.z + th[6]);
      r1[7] = r1[6] * __cosf(pb1.w + th[7]);

      _Float16 h0[8], h1[8];
#pragma unroll
      for (int i = 0; i < 8; ++i) { h0[i] = (_Float16)r0[i]; h1[i] = (_Float16)r1[i]; }

      union { v4h v[2]; float4 f; } u0, u1;
      u0.v[0] = (v4h){h0[0], h0[1], h0[2], h0[3]};
      u0.v[1] = (v4h){h0[4], h0[5], h0[6], h0[7]};
      u1.v[0] = (v4h){h1[0], h1[1], h1[2], h1[3]};
      u1.v[1] = (v4h){h1[4], h1[5], h1[6], h1[7]};
      *(float4*)&Kl[tid * 8]         = u0.f;   // 16 B/lane stride: conflict-free
      *(float4*)&Kl[(tid + 256) * 8] = u1.f;

#pragma unroll
      for (int d = 0; d < 8; ++d) {
        VT[d][tid]       = h0[d];    // b16, lane-consecutive: free
        VT[d][tid + 256] = h1[d];
      }
    }
    __syncthreads();

    // issue next chunk's x loads now; consumed after the compute phase
    if (cc + 1 < NCHUNK) {
      const int cn = (c0 + cc + 1) & (NCHUNK - 1);
      const float* xp = xb + (size_t)(cn * CHUNK + tid) * EMB;
      pa0 = *(const float4*)(xp);
      pa1 = *(const float4*)(xp + 4);
      pb0 = *(const float4*)(xp + 256 * EMB);
      pb1 = *(const float4*)(xp + 256 * EMB + 4);
    }

    // qf from Kl on the q-containing chunk (cc == 0 visits c0 first)
    if (cc == 0) {
      const v4h qsc = {(_Float16)QSCALE, (_Float16)QSCALE,
                       (_Float16)QSCALE, (_Float16)QSCALE};
      const int lbase = qb - c0 * CHUNK + ln;
      if (quad < 2) {
        qf[0] = *(const v4h*)&Kl[(lbase)      * 8 + quad * 4] * qsc;
        qf[1] = *(const v4h*)&Kl[(lbase + 16) * 8 + quad * 4] * qsc;
      }
    }

    // ---- compute: 32 16-key tiles, 2 q-tiles each ----
#pragma unroll 4
    for (int t16 = 0; t16 < CHUNK / 16; ++t16) {
      const v4h kf = *(const v4h*)&Kl[(t16 * 16 + ln) * 8 + (quad & 1) * 4];
      const v4h vt = *(const v4h*)&VT[ln][t16 * 16 + quad * 4];
#pragma unroll
      for (int t = 0; t < 2; ++t) {
        const v4f s = __builtin_amdgcn_mfma_f32_16x16x16f16(kf, qf[t], zf, 0, 0, 0);
        union { v2fp p[2]; v4h v; } pk;
        pk.p[0] = __builtin_amdgcn_cvt_pkrtz(__builtin_amdgcn_exp2f(s[0]),
                                             __builtin_amdgcn_exp2f(s[1]));
        pk.p[1] = __builtin_amdgcn_cvt_pkrtz(__builtin_amdgcn_exp2f(s[2]),
                                             __builtin_amdgcn_exp2f(s[3]));
        acc[t] = __builtin_amdgcn_mfma_f32_16x16x16f16(vt, pk.v, acc[t], 0, 0, 0);
      }
    }
  }

  // epilogue: acc[t] = out^T[d=quad*4+r][q=ln]; den at d=8 = lane 32+ln, r=0
#pragma unroll
  for (int t = 0; t < 2; ++t) {
    const float den = __shfl(acc[t][0], 32 + ln, 64);
    const float inv = 1.0f / den;
    if (quad < 2) {
      const int qrow = qb + t * 16 + ln;
      v4h o = {(_Float16)(acc[t][0] * inv), (_Float16)(acc[t][1] * inv),
               (_Float16)(acc[t][2] * inv), (_Float16)(acc[t][3] * inv)};
      *(v4h*)(Ah + ((size_t)b * SEQ + qrow) * EMB + h * DK + quad * 4) = o;
    }
  }
}

// ---------------------------------------------------------------------------
// MFMA projection (unchanged from R10/R11). out = Ah · W^T, fp32 out.
// W converted f32->f16 during LDS staging. W row-major IS the B-fragment
// source: B[k][n] = W[n][k] -> lane reads Whs[n=ln][k=quad*4+j].
// Block: 64 rows x 64 cols (grid 256x2) -> LDS 35 KB, 4 blocks/CU.
// ---------------------------------------------------------------------------
__launch_bounds__(256, 4)
__global__ void proj_kernel(const _Float16* __restrict__ Ah,
                            const float* __restrict__ W,
                            float* __restrict__ out) {
  __shared__ __align__(16) _Float16 Ahs[64][136];    // 17.4 KB
  __shared__ __align__(16) _Float16 Whs[64][136];    // 17.4 KB

  const int tid  = threadIdx.x;
  const int L    = tid & 63;
  const int wv   = tid >> 6;
  const int quad = L >> 4;
  const int ln   = L & 15;
  const int rowbase = blockIdx.x * 64;
  const int colbase = blockIdx.y * 64;

#pragma unroll
  for (int it = 0; it < 4; ++it) {
    const int idx = it * 256 + tid;
    const int r  = idx >> 4;
    const int c8 = idx & 15;
    *(uint4*)&Ahs[r][c8 * 8] =
        *(const uint4*)(Ah + (size_t)(rowbase + r) * EMB + c8 * 8);
  }
#pragma unroll
  for (int it = 0; it < 8; ++it) {
    const int idx = it * 256 + tid;
    const int n  = idx >> 5;
    const int c4 = idx & 31;
    const float4 w = *(const float4*)(W + (size_t)(colbase + n) * EMB + c4 * 4);
    v4h wh = {(_Float16)w.x, (_Float16)w.y, (_Float16)w.z, (_Float16)w.w};
    *(v4h*)&Whs[n][c4 * 4] = wh;
  }
  __syncthreads();

  v4f acc[4];
#pragma unroll
  for (int nt = 0; nt < 4; ++nt) acc[nt] = (v4f){0.f, 0.f, 0.f, 0.f};

#pragma unroll
  for (int k8 = 0; k8 < 8; ++k8) {
    const v4h af = *(const v4h*)&Ahs[wv * 16 + ln][k8 * 16 + quad * 4];
#pragma unroll
    for (int nt = 0; nt < 4; ++nt) {
      const v4h bf = *(const v4h*)&Whs[nt * 16 + ln][k8 * 16 + quad * 4];
      acc[nt] = __builtin_amdgcn_mfma_f32_16x16x16f16(af, bf, acc[nt], 0, 0, 0);
    }
  }

#pragma unroll
  for (int nt = 0; nt < 4; ++nt) {
    const int col = colbase + nt * 16 + ln;
#pragma unroll
    for (int r = 0; r < 4; ++r) {
      out[(size_t)(rowbase + wv * 16 + quad * 4 + r) * EMB + col] = acc[nt][r];
    }
  }
}

// ---------------------------------------------------------------------------
extern "C" void kernel_launch(void* const* d_in, const int* in_sizes, int n_in,
                              void* d_out, int out_size, void* d_ws, size_t ws_size,
                              hipStream_t stream) {
  const float* x     = (const float*)d_in[0];  // [4,2048,128]
  const float* theta = (const float*)d_in[1];  // [8]
  const float* w_out = (const float*)d_in[2];  // [128,128]
  float* out = (float*)d_out;                  // [4,2048,128]

  _Float16* Ah = (_Float16*)d_ws;              // [16384][128] f16 = 4 MB

  // fused features + attention: 64 bh x 16 q-chunks = 1024 blocks, 4 waves
  attn_kernel<<<dim3(1024), dim3(256), 0, stream>>>(x, theta, Ah);

  // projection: 256 row-tiles x 2 col-tiles
  proj_kernel<<<dim3((BATCH * SEQ) / 64, 2), dim3(256), 0, stream>>>(Ah, w_out, out);
}